// Round 8
// baseline (85.393 us; speedup 1.0000x reference)
//
#include <hip/hip_runtime.h>
#include <hip/hip_bf16.h>
#include <math.h>

typedef float  f32x4  __attribute__((ext_vector_type(4)));
typedef float  f32x16 __attribute__((ext_vector_type(16)));
typedef short  s16x8  __attribute__((ext_vector_type(8)));
typedef unsigned int u32x4 __attribute__((ext_vector_type(4)));

constexpr int kNRays = 16384;
constexpr int kOffDepth   = kNRays * 3;
constexpr int kOffAcc     = kOffDepth + kNRays;
constexpr int kOffWeights = kOffAcc + kNRays;

// ws layout (ushort units). A-fragments for 32x32x16: frag f=(mt*KS+ks), lane l, e:
//   value = W[k = ks*16 + (l>>5)*8 + e][m = mt*32 + (l&31)]  (with per-layer pad/rotate)
constexpr int kAg0 = 0;      // 32x64:  MT=2 KS=2 -> 2048
constexpr int kAg1 = 2048;   // 64x64:  MT=2 KS=4 -> 4096
constexpr int kAd  = 6144;   // 64x32(pad16, rotated): MT=1 KS=4 -> 2048
constexpr int kAc0 = 8192;   // 32x64 (24 real + bias row 24): MT=2 KS=2 -> 2048
constexpr int kAc1 = 10240;  // 64x64 -> 4096
constexpr int kAc2 = 14336;  // 64x64 -> 4096
constexpr int kAch = 18432;  // 64x32(pad3): MT=1 KS=4 -> 2048
constexpr int kFb  = 20480;  // 64 f32: [0..31] rotated bd (pad 0), [32..63] bch (pad 0)
constexpr int kPrepTotal = 20480 + 64;

__device__ __forceinline__ ushort f2bf(float x) {
    unsigned u = __float_as_uint(x);
    return (ushort)((u + 0x7FFFu + ((u >> 16) & 1u)) >> 16);
}
__device__ __forceinline__ unsigned pk2(float lo, float hi) {
    __hip_bfloat162 hh = __float22bfloat162_rn(float2{lo, hi});
    return *reinterpret_cast<unsigned*>(&hh);   // v_cvt_pk_bf16_f32
}
__device__ __forceinline__ float wave_sum(float v) {
#pragma unroll
    for (int off = 32; off > 0; off >>= 1) v += __shfl_xor(v, off, 64);
    return v;
}

// One-time weight staging into 32x32x16 A-fragment layout.
__global__ __launch_bounds__(256) void prep_weights(
    const float* __restrict__ Wg0, const float* __restrict__ Wg1,
    const float* __restrict__ Wd,  const float* __restrict__ Wc0,
    const float* __restrict__ Wc1, const float* __restrict__ Wc2,
    const float* __restrict__ Wch, const float* __restrict__ bc0,
    const float* __restrict__ bd,  const float* __restrict__ bch,
    ushort* __restrict__ ws)
{
    const int i = blockIdx.x * 256 + threadIdx.x;
    if (i >= kPrepTotal) return;
    if (i < kFb) {
        const float* W; int KS, base, mode = 0;   // 0 plain, 1 d, 2 c0, 3 ch
        if (i < kAg1)      { W = Wg0; KS = 2; base = kAg0; }
        else if (i < kAd)  { W = Wg1; KS = 4; base = kAg1; }
        else if (i < kAc0) { W = Wd;  KS = 4; base = kAd;  mode = 1; }
        else if (i < kAc1) { W = Wc0; KS = 2; base = kAc0; mode = 2; }
        else if (i < kAc2) { W = Wc1; KS = 4; base = kAc1; }
        else if (i < kAch) { W = Wc2; KS = 4; base = kAc2; }
        else               { W = Wch; KS = 4; base = kAch; mode = 3; }
        const int r = i - base;
        const int e = r & 7, l = (r >> 3) & 63, f = r >> 9;
        const int ks = f % KS, mt = f / KS;
        const int m = mt * 32 + (l & 31);
        const int k = ks * 16 + (l >> 5) * 8 + e;
        float w = 0.f;
        if (mode == 0)      w = W[k * 64 + m];
        else if (mode == 1) w = (m < 15) ? W[k * 16 + m + 1] : (m == 15 ? W[k * 16] : 0.f);
        else if (mode == 2) w = (k < 24) ? W[k * 64 + m] : (k == 24 ? bc0[m] : 0.f);
        else                w = (m < 3) ? W[k * 3 + m] : 0.f;
        ws[i] = f2bf(w);
    } else {
        float* fb = (float*)(ws + kFb);
        const int t = i - kFb;
        float v = 0.f;
        if (t < 32) { if (t < 15) v = bd[t + 1]; else if (t == 15) v = bd[0]; }
        else        { const int tt = t - 32; if (tt < 3) v = bch[tt]; }
        fb[t] = v;
    }
}

// One 64-out layer in 32x32 tiles: Bi[KS][2] -> Bo[4][2], relu, all reg->reg.
template<int KS, bool HASBIAS>
__device__ __forceinline__ void layer32(const u32x4 (*__restrict__ Bi)[2],
                                        const ushort* __restrict__ Aws,
                                        const float* __restrict__ bias,
                                        int h, int lane,
                                        u32x4 (*__restrict__ Bo)[2]) {
#pragma unroll
    for (int mt = 0; mt < 2; ++mt) {
        s16x8 A[KS];
#pragma unroll
        for (int ks = 0; ks < KS; ++ks)
            A[ks] = *(const s16x8*)&Aws[((mt * KS + ks) * 64 + lane) * 8];
        f32x4 bq[4];
#pragma unroll
        for (int r8 = 0; r8 < 4; ++r8) {
            if constexpr (HASBIAS)
                bq[r8] = *(const f32x4*)(bias + mt * 32 + 4 * h + 8 * r8);
            else
                bq[r8] = (f32x4){0.f, 0.f, 0.f, 0.f};
        }
#pragma unroll
        for (int nt = 0; nt < 2; ++nt) {
            f32x16 acc;
#pragma unroll
            for (int r8 = 0; r8 < 4; ++r8) {
                acc[4 * r8 + 0] = bq[r8].x; acc[4 * r8 + 1] = bq[r8].y;
                acc[4 * r8 + 2] = bq[r8].z; acc[4 * r8 + 3] = bq[r8].w;
            }
#pragma unroll
            for (int ks = 0; ks < KS; ++ks)
                acc = __builtin_amdgcn_mfma_f32_32x32x16_bf16(
                    A[ks], *(const s16x8*)&Bi[ks][nt], acc, 0, 0, 0);
            unsigned q[4][2];
#pragma unroll
            for (int r8 = 0; r8 < 4; ++r8)
#pragma unroll
                for (int t = 0; t < 2; ++t)
                    q[r8][t] = pk2(fmaxf(acc[4 * r8 + 2 * t], 0.f),
                                   fmaxf(acc[4 * r8 + 2 * t + 1], 0.f));
#pragma unroll
            for (int kk = 0; kk < 2; ++kk) {
                auto s0 = __builtin_amdgcn_permlane32_swap(q[2 * kk][0], q[2 * kk + 1][0], false, false);
                auto s1 = __builtin_amdgcn_permlane32_swap(q[2 * kk][1], q[2 * kk + 1][1], false, false);
                Bo[2 * mt + kk][nt] = (u32x4){ s0[0], s1[0], s0[1], s1[1] };
            }
        }
    }
}

__global__ __launch_bounds__(256, 3) void nerf_mfma_kernel(
    const float* __restrict__ rays_o, const float* __restrict__ rays_d,
    const float* __restrict__ tables, const ushort* __restrict__ ws,
    const float* __restrict__ bg0, const float* __restrict__ bg1,
    const float* __restrict__ bc1, const float* __restrict__ bc2,
    float* __restrict__ out)
{
    const int tid  = threadIdx.x;
    const int wid  = tid >> 6;
    const int lane = tid & 63;
    const int c    = lane & 31;
    const int h    = lane >> 5;
    const int ray  = blockIdx.x * 4 + wid;

    const float ox = rays_o[ray * 3 + 0], oy = rays_o[ray * 3 + 1], oz = rays_o[ray * 3 + 2];
    const float dx = rays_d[ray * 3 + 0], dy = rays_d[ray * 3 + 1], dz = rays_d[ray * 3 + 2];

    const float step = 1.0f / 63.0f;
    const float z  = 0.1f + 1.4f * ((float)lane * step);
    const float zn = 0.1f + 1.4f * ((float)(lane + 1) * step);

    // ---- hash gather straight into g0 B-fragments ----
    // B[k = 16ks + 8h + e][n = nt*32 + c]; k -> level (k>>1) = 8ks+4h+j, feat k&1
    const float2* __restrict__ tb = (const float2*)tables;
    u32x4 B0[2][2];
#pragma unroll
    for (int nt = 0; nt < 2; ++nt) {
        const int s = nt * 32 + c;
        const float ts = (float)s * step;
        const float zs = fmaf(1.4f, ts, 0.1f);
        const float px = fmaf(dx, zs, ox), py = fmaf(dy, zs, oy), pz = fmaf(dz, zs, oz);
#pragma unroll
        for (int ks = 0; ks < 2; ++ks) {
            u32x4 val;
#pragma unroll
            for (int j = 0; j < 4; ++j) {
                const int lv = 8 * ks + 4 * h + j;
                const float res = (float)(32 << lv);
                const float rm1 = res - 1.0f;
                const float hf = 0.5f * rm1;
                const float sx = __builtin_amdgcn_fmed3f(fmaf(px, hf, hf), 0.f, rm1);
                const float sy = __builtin_amdgcn_fmed3f(fmaf(py, hf, hf), 0.f, rm1);
                const float sz = __builtin_amdgcn_fmed3f(fmaf(pz, hf, hf), 0.f, rm1);
                const float idxf = fmaf(sx, res * res, fmaf(sy, res, sz));
                const float szm1 = (lv == 0) ? 32767.f : (lv == 1) ? 262143.f : 524287.f;
                const unsigned idx = (unsigned)(int)fminf(idxf, szm1);
                const float2 f2 = tb[((unsigned)lv << 19) + idx];
                val[j] = pk2(f2.x, f2.y);
            }
            B0[ks][nt] = val;
        }
    }

    // ---- geo MLP ----
    u32x4 B1[4][2], B2[4][2];
    layer32<2, true>(B0, ws + kAg0, bg0, h, lane, B1);
    layer32<4, true>(B1, ws + kAg1, bg1, h, lane, B2);

    // ---- d: 64 -> 32(pad), rotated (row15 = geo[0] logit), no relu ----
    const float* fb = (const float*)(ws + kFb);
    u32x4 Bc0[2][2];
    float lg0 = 0.f, lg1 = 0.f;
    {
        s16x8 Ad[4];
#pragma unroll
        for (int ks = 0; ks < 4; ++ks)
            Ad[ks] = *(const s16x8*)&ws[kAd + (ks * 64 + lane) * 8];
#pragma unroll
        for (int nt = 0; nt < 2; ++nt) {
            f32x16 acc;
#pragma unroll
            for (int r8 = 0; r8 < 4; ++r8) {
                const f32x4 bq = *(const f32x4*)(fb + 4 * h + 8 * r8);
                acc[4 * r8 + 0] = bq.x; acc[4 * r8 + 1] = bq.y;
                acc[4 * r8 + 2] = bq.z; acc[4 * r8 + 3] = bq.w;
            }
#pragma unroll
            for (int ks = 0; ks < 4; ++ks)
                acc = __builtin_amdgcn_mfma_f32_32x32x16_bf16(
                    Ad[ks], *(const s16x8*)&B2[ks][nt], acc, 0, 0, 0);
            if (nt == 0) lg0 = acc[7]; else lg1 = acc[7];   // row 15 (h=1, reg 7)
            if (h) acc[7] = 0.5f;                            // c_in row 15 := SH[0]
            const unsigned q00 = pk2(acc[0], acc[1]), q01 = pk2(acc[2], acc[3]);
            const unsigned q10 = pk2(acc[4], acc[5]), q11 = pk2(acc[6], acc[7]);
            auto s0 = __builtin_amdgcn_permlane32_swap(q00, q10, false, false);
            auto s1 = __builtin_amdgcn_permlane32_swap(q01, q11, false, false);
            Bc0[0][nt] = (u32x4){ s0[0], s1[0], s0[1], s1[1] };
        }
    }
    float lgit;
    {
        auto sl = __builtin_amdgcn_permlane32_swap(__float_as_uint(lg0), __float_as_uint(lg1), false, false);
        lgit = __uint_as_float(sl[1]);
    }
    {   // c_in rows 16..31: SH (h=0) / bias-1 + pad (h=1), ray-uniform
        u32x4 wloc;
        if (h == 0) wloc = (u32x4){ pk2(dx, dy), pk2(dz, dx * dy), pk2(dx * dz, dy * dz),
                                    pk2(dx * dx - dy * dy, 3.f * dz * dz - 1.f) };
        else        wloc = (u32x4){ 0x00003F80u, 0u, 0u, 0u };
        Bc0[1][0] = wloc; Bc0[1][1] = wloc;
    }

    // ---- color MLP ----
    u32x4 B3[4][2], B4[4][2], B5[4][2];
    layer32<2, false>(Bc0, ws + kAc0, nullptr, h, lane, B3);   // bias folded at k=24
    layer32<4, true >(B3,  ws + kAc1, bc1,     h, lane, B4);
    layer32<4, true >(B4,  ws + kAc2, bc2,     h, lane, B5);

    // ---- ch: 64 -> 32(pad3) ----
    f32x16 acch[2];
    {
        s16x8 Ah[4];
#pragma unroll
        for (int ks = 0; ks < 4; ++ks)
            Ah[ks] = *(const s16x8*)&ws[kAch + (ks * 64 + lane) * 8];
#pragma unroll
        for (int nt = 0; nt < 2; ++nt) {
            f32x16 acc;
#pragma unroll
            for (int r8 = 0; r8 < 4; ++r8) {
                const f32x4 bq = *(const f32x4*)(fb + 32 + 4 * h + 8 * r8);
                acc[4 * r8 + 0] = bq.x; acc[4 * r8 + 1] = bq.y;
                acc[4 * r8 + 2] = bq.z; acc[4 * r8 + 3] = bq.w;
            }
#pragma unroll
            for (int ks = 0; ks < 4; ++ks)
                acc = __builtin_amdgcn_mfma_f32_32x32x16_bf16(
                    Ah[ks], *(const s16x8*)&B5[ks][nt], acc, 0, 0, 0);
            acch[nt] = acc;
        }
    }
    // rows 0..2 (h=0 lanes regs 0..2) -> lane = sample via swap .x
    auto sw0 = __builtin_amdgcn_permlane32_swap(__float_as_uint(acch[0][0]), __float_as_uint(acch[1][0]), false, false);
    auto sw1 = __builtin_amdgcn_permlane32_swap(__float_as_uint(acch[0][1]), __float_as_uint(acch[1][1]), false, false);
    auto sw2 = __builtin_amdgcn_permlane32_swap(__float_as_uint(acch[0][2]), __float_as_uint(acch[1][2]), false, false);
    const float lr  = __uint_as_float(sw0[0]);
    const float lgr = __uint_as_float(sw1[0]);
    const float lb  = __uint_as_float(sw2[0]);

    const float cr = 1.f / (1.f + expf(-lr));
    const float cg = 1.f / (1.f + expf(-lgr));
    const float cb = 1.f / (1.f + expf(-lb));
    const float gx = lgit - 1.0f;
    const float density = fmaxf(gx, 0.f) + log1pf(expf(-fabsf(gx)));

    // ---- volume rendering (lane = sample) ----
    const float dnorm = sqrtf(dx * dx + dy * dy + dz * dz);
    float dist = (lane < 63) ? (zn - z) : 1e10f;
    dist *= dnorm;
    const float alpha = 1.0f - expf(-density * dist);
    float f = 1.0f - alpha + 1e-10f;
#pragma unroll
    for (int off = 1; off < 64; off <<= 1) {
        const float gg = __shfl_up(f, off, 64);
        if (lane >= off) f *= gg;
    }
    float T = __shfl_up(f, 1, 64);
    if (lane == 0) T = 1.0f;
    const float w = alpha * T;

    out[kOffWeights + ray * 64 + lane] = w;
    const float sr = wave_sum(w * cr);
    const float sg = wave_sum(w * cg);
    const float sb = wave_sum(w * cb);
    const float sd = wave_sum(w * z);
    const float sa = wave_sum(w);
    if (lane == 0) {
        out[ray * 3 + 0] = sr;
        out[ray * 3 + 1] = sg;
        out[ray * 3 + 2] = sb;
        out[kOffDepth + ray] = sd;
        out[kOffAcc + ray]   = sa;
    }
}

extern "C" void kernel_launch(void* const* d_in, const int* in_sizes, int n_in,
                              void* d_out, int out_size, void* d_ws, size_t ws_size,
                              hipStream_t stream) {
    const float* rays_o = (const float*)d_in[0];
    const float* rays_d = (const float*)d_in[1];
    const float* tables = (const float*)d_in[2];
    const float* Wg0 = (const float*)d_in[3];
    const float* bg0 = (const float*)d_in[4];
    const float* Wg1 = (const float*)d_in[5];
    const float* bg1 = (const float*)d_in[6];
    const float* Wd  = (const float*)d_in[7];
    const float* bd  = (const float*)d_in[8];
    const float* Wc0 = (const float*)d_in[9];
    const float* bc0 = (const float*)d_in[10];
    const float* Wc1 = (const float*)d_in[11];
    const float* bc1 = (const float*)d_in[12];
    const float* Wc2 = (const float*)d_in[13];
    const float* bc2 = (const float*)d_in[14];
    const float* Wch = (const float*)d_in[15];
    const float* bch = (const float*)d_in[16];
    float* out = (float*)d_out;
    ushort* wsp = (ushort*)d_ws;

    prep_weights<<<dim3((kPrepTotal + 255) / 256), dim3(256), 0, stream>>>(
        Wg0, Wg1, Wd, Wc0, Wc1, Wc2, Wch, bc0, bd, bch, wsp);

    nerf_mfma_kernel<<<dim3(kNRays / 4), dim3(256), 0, stream>>>(
        rays_o, rays_d, tables, wsp,
        bg0, bg1, bc1, bc2, out);
}

// Round 9
// 81.017 us; speedup vs baseline: 1.0540x; 1.0540x over previous
//
#include <hip/hip_runtime.h>
#include <hip/hip_bf16.h>
#include <math.h>

typedef float  f32x4  __attribute__((ext_vector_type(4)));
typedef float  f32x16 __attribute__((ext_vector_type(16)));
typedef short  s16x8  __attribute__((ext_vector_type(8)));
typedef unsigned int u32x4 __attribute__((ext_vector_type(4)));

constexpr int kNRays = 16384;
constexpr int kOffDepth   = kNRays * 3;
constexpr int kOffAcc     = kOffDepth + kNRays;
constexpr int kOffWeights = kOffAcc + kNRays;

// ws layout (ushort units). A-fragments for 32x32x16: frag f=(mt*KS+ks), lane l, e:
//   value = W[k = ks*16 + (l>>5)*8 + e][m = mt*32 + (l&31)]  (with per-layer pad/rotate)
constexpr int kAg0 = 0;      // 32x64:  MT=2 KS=2 -> 2048
constexpr int kAg1 = 2048;   // 64x64:  MT=2 KS=4 -> 4096
constexpr int kAd  = 6144;   // 64x32(pad16, rotated): MT=1 KS=4 -> 2048
constexpr int kAc0 = 8192;   // 32x64 (24 real + bias row 24): MT=2 KS=2 -> 2048
constexpr int kAc1 = 10240;  // 64x64 -> 4096
constexpr int kAc2 = 14336;  // 64x64 -> 4096
constexpr int kAch = 18432;  // 64x32(pad3): MT=1 KS=4 -> 2048
constexpr int kFb  = 20480;  // 64 f32: [0..31] rotated bd (pad 0), [32..63] bch (pad 0)
constexpr int kPrepTotal = 20480 + 64;

__device__ __forceinline__ ushort f2bf(float x) {
    unsigned u = __float_as_uint(x);
    return (ushort)((u + 0x7FFFu + ((u >> 16) & 1u)) >> 16);
}
__device__ __forceinline__ unsigned pk2(float lo, float hi) {
    __hip_bfloat162 hh = __float22bfloat162_rn(float2{lo, hi});
    return *reinterpret_cast<unsigned*>(&hh);   // v_cvt_pk_bf16_f32
}
__device__ __forceinline__ float wave_sum(float v) {
#pragma unroll
    for (int off = 32; off > 0; off >>= 1) v += __shfl_xor(v, off, 64);
    return v;
}

// One-time weight staging into 32x32x16 A-fragment layout.
__global__ __launch_bounds__(256) void prep_weights(
    const float* __restrict__ Wg0, const float* __restrict__ Wg1,
    const float* __restrict__ Wd,  const float* __restrict__ Wc0,
    const float* __restrict__ Wc1, const float* __restrict__ Wc2,
    const float* __restrict__ Wch, const float* __restrict__ bc0,
    const float* __restrict__ bd,  const float* __restrict__ bch,
    ushort* __restrict__ ws)
{
    const int i = blockIdx.x * 256 + threadIdx.x;
    if (i >= kPrepTotal) return;
    if (i < kFb) {
        const float* W; int KS, base, mode = 0;   // 0 plain, 1 d, 2 c0, 3 ch
        if (i < kAg1)      { W = Wg0; KS = 2; base = kAg0; }
        else if (i < kAd)  { W = Wg1; KS = 4; base = kAg1; }
        else if (i < kAc0) { W = Wd;  KS = 4; base = kAd;  mode = 1; }
        else if (i < kAc1) { W = Wc0; KS = 2; base = kAc0; mode = 2; }
        else if (i < kAc2) { W = Wc1; KS = 4; base = kAc1; }
        else if (i < kAch) { W = Wc2; KS = 4; base = kAc2; }
        else               { W = Wch; KS = 4; base = kAch; mode = 3; }
        const int r = i - base;
        const int e = r & 7, l = (r >> 3) & 63, f = r >> 9;
        const int ks = f % KS, mt = f / KS;
        const int m = mt * 32 + (l & 31);
        const int k = ks * 16 + (l >> 5) * 8 + e;
        float w = 0.f;
        if (mode == 0)      w = W[k * 64 + m];
        else if (mode == 1) w = (m < 15) ? W[k * 16 + m + 1] : (m == 15 ? W[k * 16] : 0.f);
        else if (mode == 2) w = (k < 24) ? W[k * 64 + m] : (k == 24 ? bc0[m] : 0.f);
        else                w = (m < 3) ? W[k * 3 + m] : 0.f;
        ws[i] = f2bf(w);
    } else {
        float* fb = (float*)(ws + kFb);
        const int t = i - kFb;
        float v = 0.f;
        if (t < 32) { if (t < 15) v = bd[t + 1]; else if (t == 15) v = bd[0]; }
        else        { const int tt = t - 32; if (tt < 3) v = bch[tt]; }
        fb[t] = v;
    }
}

// One 64-out layer in 32x32 tiles over 4 N-tiles (2 rays x 2): reg->reg, relu.
template<int KS, bool HASBIAS>
__device__ __forceinline__ void layer32(const u32x4 (*__restrict__ Bi)[4],
                                        const ushort* __restrict__ Aws,
                                        const float* __restrict__ bias,
                                        int h, int lane,
                                        u32x4 (*__restrict__ Bo)[4]) {
#pragma unroll
    for (int mt = 0; mt < 2; ++mt) {
        s16x8 A[KS];
#pragma unroll
        for (int ks = 0; ks < KS; ++ks)
            A[ks] = *(const s16x8*)&Aws[((mt * KS + ks) * 64 + lane) * 8];
        f32x4 bq[4];
#pragma unroll
        for (int r8 = 0; r8 < 4; ++r8) {
            if constexpr (HASBIAS)
                bq[r8] = *(const f32x4*)(bias + mt * 32 + 4 * h + 8 * r8);
            else
                bq[r8] = (f32x4){0.f, 0.f, 0.f, 0.f};
        }
#pragma unroll
        for (int nt = 0; nt < 4; ++nt) {
            f32x16 acc;
#pragma unroll
            for (int r8 = 0; r8 < 4; ++r8) {
                acc[4 * r8 + 0] = bq[r8].x; acc[4 * r8 + 1] = bq[r8].y;
                acc[4 * r8 + 2] = bq[r8].z; acc[4 * r8 + 3] = bq[r8].w;
            }
#pragma unroll
            for (int ks = 0; ks < KS; ++ks)
                acc = __builtin_amdgcn_mfma_f32_32x32x16_bf16(
                    A[ks], *(const s16x8*)&Bi[ks][nt], acc, 0, 0, 0);
            unsigned q[4][2];
#pragma unroll
            for (int r8 = 0; r8 < 4; ++r8)
#pragma unroll
                for (int t = 0; t < 2; ++t)
                    q[r8][t] = pk2(fmaxf(acc[4 * r8 + 2 * t], 0.f),
                                   fmaxf(acc[4 * r8 + 2 * t + 1], 0.f));
#pragma unroll
            for (int kk = 0; kk < 2; ++kk) {
                auto s0 = __builtin_amdgcn_permlane32_swap(q[2 * kk][0], q[2 * kk + 1][0], false, false);
                auto s1 = __builtin_amdgcn_permlane32_swap(q[2 * kk][1], q[2 * kk + 1][1], false, false);
                Bo[2 * mt + kk][nt] = (u32x4){ s0[0], s1[0], s0[1], s1[1] };
            }
        }
    }
}

__global__ __launch_bounds__(256, 2) void nerf_mfma_kernel(
    const float* __restrict__ rays_o, const float* __restrict__ rays_d,
    const float* __restrict__ tables, const ushort* __restrict__ ws,
    const float* __restrict__ bg0, const float* __restrict__ bg1,
    const float* __restrict__ bc1, const float* __restrict__ bc2,
    float* __restrict__ out)
{
    const int tid  = threadIdx.x;
    const int wid  = tid >> 6;
    const int lane = tid & 63;
    const int c    = lane & 31;
    const int h    = lane >> 5;
    const int ray0 = blockIdx.x * 8 + wid * 2;   // this wave owns rays ray0, ray0+1

    float o3[2][3], d3[2][3];
#pragma unroll
    for (int r = 0; r < 2; ++r) {
        o3[r][0] = rays_o[(ray0 + r) * 3 + 0];
        o3[r][1] = rays_o[(ray0 + r) * 3 + 1];
        o3[r][2] = rays_o[(ray0 + r) * 3 + 2];
        d3[r][0] = rays_d[(ray0 + r) * 3 + 0];
        d3[r][1] = rays_d[(ray0 + r) * 3 + 1];
        d3[r][2] = rays_d[(ray0 + r) * 3 + 2];
    }

    const float step = 1.0f / 63.0f;
    const float z  = 0.1f + 1.4f * ((float)lane * step);
    const float zn = 0.1f + 1.4f * ((float)(lane + 1) * step);

    // ---- hash gather into g0 B-fragments for both rays (32 loads in flight) ----
    // nt tile: nt<2 -> ray0 samples nt*32+c ; nt>=2 -> ray1 samples (nt-2)*32+c
    const float2* __restrict__ tb = (const float2*)tables;
    u32x4 B0[2][4];
#pragma unroll
    for (int nt = 0; nt < 4; ++nt) {
        const int r = nt >> 1;
        const int s = (nt & 1) * 32 + c;
        const float ts = (float)s * step;
        const float zs = fmaf(1.4f, ts, 0.1f);
        const float px = fmaf(d3[r][0], zs, o3[r][0]);
        const float py = fmaf(d3[r][1], zs, o3[r][1]);
        const float pz = fmaf(d3[r][2], zs, o3[r][2]);
#pragma unroll
        for (int ks = 0; ks < 2; ++ks) {
            u32x4 val;
#pragma unroll
            for (int j = 0; j < 4; ++j) {
                const int lv = 8 * ks + 4 * h + j;
                const float res = (float)(32 << lv);
                const float rm1 = res - 1.0f;
                const float hf = 0.5f * rm1;
                const float sx = __builtin_amdgcn_fmed3f(fmaf(px, hf, hf), 0.f, rm1);
                const float sy = __builtin_amdgcn_fmed3f(fmaf(py, hf, hf), 0.f, rm1);
                const float sz = __builtin_amdgcn_fmed3f(fmaf(pz, hf, hf), 0.f, rm1);
                const float idxf = fmaf(sx, res * res, fmaf(sy, res, sz));
                const float szm1 = (lv == 0) ? 32767.f : (lv == 1) ? 262143.f : 524287.f;
                const unsigned idx = (unsigned)(int)fminf(idxf, szm1);
                const float2 f2 = tb[((unsigned)lv << 19) + idx];
                val[j] = pk2(f2.x, f2.y);
            }
            B0[ks][nt] = val;
        }
    }

    // ---- geo MLP ----
    u32x4 B1[4][4], B2[4][4];
    layer32<2, true>(B0, ws + kAg0, bg0, h, lane, B1);
    layer32<4, true>(B1, ws + kAg1, bg1, h, lane, B2);

    // ---- d: 64 -> 32(pad), rotated (row15 = geo[0] logit), no relu ----
    const float* fb = (const float*)(ws + kFb);
    u32x4 Bc0[2][4];
    float lgd[4];
    {
        s16x8 Ad[4];
#pragma unroll
        for (int ks = 0; ks < 4; ++ks)
            Ad[ks] = *(const s16x8*)&ws[kAd + (ks * 64 + lane) * 8];
#pragma unroll
        for (int nt = 0; nt < 4; ++nt) {
            f32x16 acc;
#pragma unroll
            for (int r8 = 0; r8 < 4; ++r8) {
                const f32x4 bq = *(const f32x4*)(fb + 4 * h + 8 * r8);
                acc[4 * r8 + 0] = bq.x; acc[4 * r8 + 1] = bq.y;
                acc[4 * r8 + 2] = bq.z; acc[4 * r8 + 3] = bq.w;
            }
#pragma unroll
            for (int ks = 0; ks < 4; ++ks)
                acc = __builtin_amdgcn_mfma_f32_32x32x16_bf16(
                    Ad[ks], *(const s16x8*)&B2[ks][nt], acc, 0, 0, 0);
            lgd[nt] = acc[7];            // row 15 (h=1 lanes, reg 7)
            if (h) acc[7] = 0.5f;        // c_in row 15 := SH[0]
            const unsigned q00 = pk2(acc[0], acc[1]), q01 = pk2(acc[2], acc[3]);
            const unsigned q10 = pk2(acc[4], acc[5]), q11 = pk2(acc[6], acc[7]);
            auto s0 = __builtin_amdgcn_permlane32_swap(q00, q10, false, false);
            auto s1 = __builtin_amdgcn_permlane32_swap(q01, q11, false, false);
            Bc0[0][nt] = (u32x4){ s0[0], s1[0], s0[1], s1[1] };
        }
    }
    float lgit[2];
#pragma unroll
    for (int r = 0; r < 2; ++r) {
        auto sl = __builtin_amdgcn_permlane32_swap(__float_as_uint(lgd[2 * r]),
                                                   __float_as_uint(lgd[2 * r + 1]), false, false);
        lgit[r] = __uint_as_float(sl[1]);
    }
#pragma unroll
    for (int r = 0; r < 2; ++r) {   // c_in rows 16..31 per ray
        const float dx = d3[r][0], dy = d3[r][1], dz = d3[r][2];
        u32x4 wloc;
        if (h == 0) wloc = (u32x4){ pk2(dx, dy), pk2(dz, dx * dy), pk2(dx * dz, dy * dz),
                                    pk2(dx * dx - dy * dy, 3.f * dz * dz - 1.f) };
        else        wloc = (u32x4){ 0x00003F80u, 0u, 0u, 0u };
        Bc0[1][2 * r] = wloc; Bc0[1][2 * r + 1] = wloc;
    }

    // ---- color MLP ----
    u32x4 B3[4][4], B4[4][4], B5[4][4];
    layer32<2, false>(Bc0, ws + kAc0, nullptr, h, lane, B3);   // bias folded at k=24
    layer32<4, true >(B3,  ws + kAc1, bc1,     h, lane, B4);
    layer32<4, true >(B4,  ws + kAc2, bc2,     h, lane, B5);

    // ---- ch: 64 -> 32(pad3): keep only rows 0..2 per nt ----
    float chv[4][3];
    {
        s16x8 Ah[4];
#pragma unroll
        for (int ks = 0; ks < 4; ++ks)
            Ah[ks] = *(const s16x8*)&ws[kAch + (ks * 64 + lane) * 8];
#pragma unroll
        for (int nt = 0; nt < 4; ++nt) {
            f32x16 acc;
#pragma unroll
            for (int r8 = 0; r8 < 4; ++r8) {
                const f32x4 bq = *(const f32x4*)(fb + 32 + 4 * h + 8 * r8);
                acc[4 * r8 + 0] = bq.x; acc[4 * r8 + 1] = bq.y;
                acc[4 * r8 + 2] = bq.z; acc[4 * r8 + 3] = bq.w;
            }
#pragma unroll
            for (int ks = 0; ks < 4; ++ks)
                acc = __builtin_amdgcn_mfma_f32_32x32x16_bf16(
                    Ah[ks], *(const s16x8*)&B5[ks][nt], acc, 0, 0, 0);
            chv[nt][0] = acc[0]; chv[nt][1] = acc[1]; chv[nt][2] = acc[2];
        }
    }

    // ---- per-ray epilogue: sigmoid, softplus, scan, reductions ----
#pragma unroll
    for (int r = 0; r < 2; ++r) {
        const int ray = ray0 + r;
        const float dx = d3[r][0], dy = d3[r][1], dz = d3[r][2];
        auto sw0 = __builtin_amdgcn_permlane32_swap(__float_as_uint(chv[2*r][0]),
                                                    __float_as_uint(chv[2*r+1][0]), false, false);
        auto sw1 = __builtin_amdgcn_permlane32_swap(__float_as_uint(chv[2*r][1]),
                                                    __float_as_uint(chv[2*r+1][1]), false, false);
        auto sw2 = __builtin_amdgcn_permlane32_swap(__float_as_uint(chv[2*r][2]),
                                                    __float_as_uint(chv[2*r+1][2]), false, false);
        const float cr = 1.f / (1.f + expf(-__uint_as_float(sw0[0])));
        const float cg = 1.f / (1.f + expf(-__uint_as_float(sw1[0])));
        const float cb = 1.f / (1.f + expf(-__uint_as_float(sw2[0])));
        const float gx = lgit[r] - 1.0f;
        const float density = fmaxf(gx, 0.f) + log1pf(expf(-fabsf(gx)));

        const float dnorm = sqrtf(dx * dx + dy * dy + dz * dz);
        float dist = (lane < 63) ? (zn - z) : 1e10f;
        dist *= dnorm;
        const float alpha = 1.0f - expf(-density * dist);
        float f = 1.0f - alpha + 1e-10f;
#pragma unroll
        for (int off = 1; off < 64; off <<= 1) {
            const float gg = __shfl_up(f, off, 64);
            if (lane >= off) f *= gg;
        }
        float T = __shfl_up(f, 1, 64);
        if (lane == 0) T = 1.0f;
        const float w = alpha * T;

        out[kOffWeights + ray * 64 + lane] = w;
        const float sr = wave_sum(w * cr);
        const float sg = wave_sum(w * cg);
        const float sb = wave_sum(w * cb);
        const float sd = wave_sum(w * z);
        const float sa = wave_sum(w);
        if (lane == 0) {
            out[ray * 3 + 0] = sr;
            out[ray * 3 + 1] = sg;
            out[ray * 3 + 2] = sb;
            out[kOffDepth + ray] = sd;
            out[kOffAcc + ray]   = sa;
        }
    }
}

extern "C" void kernel_launch(void* const* d_in, const int* in_sizes, int n_in,
                              void* d_out, int out_size, void* d_ws, size_t ws_size,
                              hipStream_t stream) {
    const float* rays_o = (const float*)d_in[0];
    const float* rays_d = (const float*)d_in[1];
    const float* tables = (const float*)d_in[2];
    const float* Wg0 = (const float*)d_in[3];
    const float* bg0 = (const float*)d_in[4];
    const float* Wg1 = (const float*)d_in[5];
    const float* bg1 = (const float*)d_in[6];
    const float* Wd  = (const float*)d_in[7];
    const float* bd  = (const float*)d_in[8];
    const float* Wc0 = (const float*)d_in[9];
    const float* bc0 = (const float*)d_in[10];
    const float* Wc1 = (const float*)d_in[11];
    const float* bc1 = (const float*)d_in[12];
    const float* Wc2 = (const float*)d_in[13];
    const float* bc2 = (const float*)d_in[14];
    const float* Wch = (const float*)d_in[15];
    const float* bch = (const float*)d_in[16];
    float* out = (float*)d_out;
    ushort* wsp = (ushort*)d_ws;

    prep_weights<<<dim3((kPrepTotal + 255) / 256), dim3(256), 0, stream>>>(
        Wg0, Wg1, Wd, Wc0, Wc1, Wc2, Wch, bc0, bd, bch, wsp);

    nerf_mfma_kernel<<<dim3(kNRays / 8), dim3(256), 0, stream>>>(
        rays_o, rays_d, tables, wsp,
        bg0, bg1, bc1, bc2, out);
}